// Round 7
// baseline (323.523 us; speedup 1.0000x reference)
//
#include <hip/hip_runtime.h>

// Koopman bilinear rollout: preds[b,t,d] = (z0 @ Kd^{t+1})[b,d], D=B=256, T=512.
// Kd = (I-A)^-1(I+A), A=0.5*dt*K -> order-4 Neumann: Kd = (I+P)@S + I,
// P=A@A, S=2A+2P (exactly I+2A+2A^2+2A^3+2A^4 -- proven numerics r2-r6).
// ONE persistent kernel (256 blocks, 11 phases / 10 grid barriers) builds the
// tables + checkpoint scan (phases verified correct in r5); then one batched
// bf16-MFMA fill launch (proven r6) covers the remaining 497 timesteps.
//
// Grid barrier lesson (r5 -> r6): acquire-load PER POLL invalidates L2 every
// iteration from every spinning block = cache storm (392us, VALUBusy 4%).
// This version: RELAXED polls + s_sleep backoff + ONE release fetch_add on
// arrival + ONE agent acquire-fence on exit. Do not reintroduce acquire polls.

#define DD 256
#define TT 512
#define MATF (DD * DD)
#define LDT ((size_t)TT * (size_t)DD)
#define NBLK 256

typedef __attribute__((ext_vector_type(8))) short bf16x8;
typedef __attribute__((ext_vector_type(4))) float f32x4;

#define GLD16(g, l)                                                  \
    __builtin_amdgcn_global_load_lds(                                \
        (const __attribute__((address_space(1))) void*)(g),          \
        (__attribute__((address_space(3))) void*)(l), 16, 0, 0)

static __device__ __forceinline__ unsigned short f2bf(float f) {
    unsigned int u = __float_as_uint(f);
    u += 0x7fffu + ((u >> 16) & 1u);
    return (unsigned short)(u >> 16);
}

// ---------------- grid barrier: release-add, relaxed-poll, one acquire -----
__device__ __forceinline__ void gridbar(unsigned* cnt, int phase) {
    __syncthreads();
    if (threadIdx.x == 0) {
        __hip_atomic_fetch_add(cnt, 1u, __ATOMIC_RELEASE,
                               __HIP_MEMORY_SCOPE_AGENT);  // wbl2 once
        const unsigned target = (unsigned)phase * (unsigned)NBLK;
        while (__hip_atomic_load(cnt, __ATOMIC_RELAXED,
                                 __HIP_MEMORY_SCOPE_AGENT) < target)
            __builtin_amdgcn_s_sleep(8);  // relaxed poll: no cache invalidate
    }
    __syncthreads();
    __builtin_amdgcn_fence(__ATOMIC_ACQUIRE, "agent");  // one inv per barrier
}

__global__ void binit_kernel(unsigned* cnt) {
    if (threadIdx.x == 0) cnt[0] = 0u;
}

// ---------------- wave-level 32x16-tile f32 GEMM (K=256, K_BLK=64) ----------
// Af [64][36] (k-major), Bf [64][20]; wave-private -> no block barriers.
// amode: 0 plain A[r][k] ; 1 cs*A[r][k] ; 2 A[r][k] + (r==k)
// bmode: 0 plain B[k][c] ; 1 cs*B[k][c] ; 2 2*(cs*B[k][c] + Pq[k][c])
__device__ void gtile_compute(const float* A, size_t lda,
                              const float* B, size_t ldb,
                              const float* Pq, float cs, int amode, int bmode,
                              float* Af, float* Bf,
                              int tr, int tc, int lane, float acc[4][2]) {
    const int ar = lane & 31;
    const int akq = lane >> 5;
    const int bk = lane >> 2;
    const int bc = (lane & 3) << 2;

#pragma unroll
    for (int i = 0; i < 4; ++i) { acc[i][0] = 0.f; acc[i][1] = 0.f; }

    float4 pa[8], pb[4], pc[4];

#pragma unroll
    for (int q = 0; q < 8; ++q)
        pa[q] = *(const float4*)(A + (size_t)(tr + ar) * lda + q * 8 + akq * 4);
#pragma unroll
    for (int q = 0; q < 4; ++q) {
        pb[q] = *(const float4*)(B + (size_t)(q * 16 + bk) * ldb + tc + bc);
        if (bmode == 2)
            pc[q] = *(const float4*)(Pq + (size_t)(q * 16 + bk) * DD + tc + bc);
    }

    for (int k0 = 0; k0 < DD; k0 += 64) {
#pragma unroll
        for (int q = 0; q < 8; ++q) {
            int kb = q * 8 + akq * 4;
            float v[4] = {pa[q].x, pa[q].y, pa[q].z, pa[q].w};
#pragma unroll
            for (int i = 0; i < 4; ++i) {
                float x = v[i];
                if (amode == 1) x *= cs;
                else if (amode == 2) x += ((k0 + kb + i) == (tr + ar)) ? 1.f : 0.f;
                Af[(kb + i) * 36 + ar] = x;
            }
        }
#pragma unroll
        for (int q = 0; q < 4; ++q) {
            int kb = q * 16 + bk;
            float4 o = pb[q];
            float* op = (float*)&o;
            if (bmode == 1) {
                op[0] *= cs; op[1] *= cs; op[2] *= cs; op[3] *= cs;
            } else if (bmode == 2) {
                const float* wp = (const float*)&pc[q];
#pragma unroll
                for (int i = 0; i < 4; ++i) op[i] = 2.f * (cs * op[i] + wp[i]);
            }
            *(float4*)(Bf + kb * 20 + bc) = o;
        }
        if (k0 + 64 < DD) {
#pragma unroll
            for (int q = 0; q < 8; ++q)
                pa[q] = *(const float4*)(A + (size_t)(tr + ar) * lda + k0 + 64 +
                                         q * 8 + akq * 4);
#pragma unroll
            for (int q = 0; q < 4; ++q) {
                pb[q] = *(const float4*)(B + (size_t)(k0 + 64 + q * 16 + bk) * ldb +
                                         tc + bc);
                if (bmode == 2)
                    pc[q] = *(const float4*)(Pq + (size_t)(k0 + 64 + q * 16 + bk) * DD +
                                             tc + bc);
            }
        }
        const int ty4 = (lane >> 3) << 2;
        const int tx2 = (lane & 7) << 1;
#pragma unroll
        for (int kk = 0; kk < 64; ++kk) {
            float4 a4 = *(const float4*)(Af + kk * 36 + ty4);
            float2 b2 = *(const float2*)(Bf + kk * 20 + tx2);
            acc[0][0] = fmaf(a4.x, b2.x, acc[0][0]);
            acc[0][1] = fmaf(a4.x, b2.y, acc[0][1]);
            acc[1][0] = fmaf(a4.y, b2.x, acc[1][0]);
            acc[1][1] = fmaf(a4.y, b2.y, acc[1][1]);
            acc[2][0] = fmaf(a4.z, b2.x, acc[2][0]);
            acc[2][1] = fmaf(a4.z, b2.y, acc[2][1]);
            acc[3][0] = fmaf(a4.w, b2.x, acc[3][0]);
            acc[3][1] = fmaf(a4.w, b2.y, acc[3][1]);
        }
    }
}

__device__ __forceinline__ void epi_plain(float* C, int ldc, int tr, int tc,
                                          int lane, float acc[4][2], int addI) {
    const int r0 = tr + ((lane >> 3) << 2);
    const int c0 = tc + ((lane & 7) << 1);
#pragma unroll
    for (int i = 0; i < 4; ++i) {
        int r = r0 + i;
        float2 v = {acc[i][0], acc[i][1]};
        if (addI) {
            v.x += (r == c0) ? 1.f : 0.f;
            v.y += (r == c0 + 1) ? 1.f : 0.f;
        }
        *(float2*)(C + (size_t)r * ldc + c0) = v;
    }
}

__device__ __forceinline__ void epi_v(float* out, unsigned short* Zb, int dst,
                                      int tr, int tc, int lane, float acc[4][2]) {
    float* Of = out + (size_t)(32 * dst - 1) * DD;
    unsigned short* Zo = Zb + (size_t)dst * MATF;
    const int r0 = tr + ((lane >> 3) << 2);
    const int c0 = tc + ((lane & 7) << 1);
#pragma unroll
    for (int i = 0; i < 4; ++i) {
        int r = r0 + i;
        float2 v = {acc[i][0], acc[i][1]};
        *(float2*)(Of + (size_t)r * LDT + c0) = v;
        unsigned w = (unsigned)f2bf(v.x) | ((unsigned)f2bf(v.y) << 16);
        *(unsigned*)(Zo + (size_t)r * DD + c0) = w;
    }
}

// ---------------- persistent table kernel (11 phases, phases proven in r5) --
__global__ void __launch_bounds__(256, 1)
tabs_kernel(const float* __restrict__ z0, const float* __restrict__ Kmat,
            const float* __restrict__ log_dt, float* __restrict__ out,
            float* __restrict__ Mtab, float* __restrict__ Wtab,
            float* __restrict__ Pmat, unsigned short* __restrict__ MTb,
            unsigned short* __restrict__ Zb, unsigned* cnt) {
    __shared__ __align__(16) float pool[4][64 * 36 + 64 * 20];
    const int tid = threadIdx.x;
    const int lane = tid & 63, wid = tid >> 6;
    float* Af = pool[wid];
    float* Bf = Af + 64 * 36;
    const int wgid = blockIdx.x * 4 + wid;  // 0..1023
    const float cs = 0.5f * expf(log_dt[0]);
    float acc[4][2];

    // ph1: Zb[0] = bf16(z0)  and  P = (cs*K)@(cs*K)
    {
        int idx = blockIdx.x * 256 + tid;
        Zb[idx] = f2bf(z0[idx]);
        for (int tj = wgid; tj < 128; tj += 1024) {
            int tr = (tj >> 4) << 5, tc = (tj & 15) << 4;
            gtile_compute(Kmat, DD, Kmat, DD, nullptr, cs, 1, 1, Af, Bf, tr, tc,
                          lane, acc);
            epi_plain(Pmat, DD, tr, tc, lane, acc, 0);
        }
    }
    gridbar(cnt, 1);

    // ph2: Kd = (I+P)@S + I, S = 2*(cs*K + P)  -> Mtab[0]
    for (int tj = wgid; tj < 128; tj += 1024) {
        int tr = (tj >> 4) << 5, tc = (tj & 15) << 4;
        gtile_compute(Pmat, DD, Kmat, DD, Pmat, cs, 2, 2, Af, Bf, tr, tc, lane, acc);
        epi_plain(Mtab, DD, tr, tc, lane, acc, 1);
    }
    gridbar(cnt, 2);

    // ph3..7: M doublings: M_{mm+1+p} = M_{mm+1} @ M_p
    for (int L = 0; L < 5; ++L) {
        int p = 1 << L;
        for (int tj = wgid; tj < 128 * p; tj += 1024) {
            int mm = tj >> 7, t = tj & 127;
            int tr = (t >> 4) << 5, tc = (t & 15) << 4;
            gtile_compute(Mtab + (size_t)mm * MATF, DD,
                          Mtab + (size_t)(p - 1) * MATF, DD, nullptr, 0.f, 0, 0,
                          Af, Bf, tr, tc, lane, acc);
            epi_plain(Mtab + (size_t)(p + mm) * MATF, DD, tr, tc, lane, acc, 0);
        }
        gridbar(cnt, 3 + L);
    }

    // ph8: mtrans (MTb_j[c][k] = bf16(M_j[k][c]))  MERGED with scan level 0
    {
        float(*tle)[33] = (float(*)[33]) & pool[0][0];
        int tx = tid & 31, ty = tid >> 5;
        for (int it = 0; it < 8; ++it) {
            int id = blockIdx.x * 8 + it;
            int j = id >> 6, sub = id & 63;
            int k0 = (sub >> 3) << 5, c0 = (sub & 7) << 5;
            const float* M = Mtab + (size_t)j * MATF;
            unsigned short* MT = MTb + (size_t)j * MATF;
#pragma unroll
            for (int i = 0; i < 32; i += 8)
                tle[ty + i][tx] = M[(size_t)(k0 + ty + i) * DD + c0 + tx];
            __syncthreads();
#pragma unroll
            for (int i = 0; i < 32; i += 8)
                MT[(size_t)(c0 + ty + i) * DD + k0 + tx] = f2bf(tle[tx][ty + i]);
            __syncthreads();
        }
    }
    // ph8b..11: checkpoint scan: level s: Z_{2^s+mm} = Z_mm @ W_{2^s} (Z_0=z0),
    // plus one W-squaring job per level (s<3). W_1 = Mtab[31] = Kd^32.
    for (int s = 0; s < 4; ++s) {
        int nvec = 1 << s;
        int njobs = nvec + (s < 3 ? 1 : 0);
        const float* W = (s == 0) ? (Mtab + (size_t)31 * MATF)
                                  : (Wtab + (size_t)(s - 1) * MATF);
        for (int tj = wgid; tj < 128 * njobs; tj += 1024) {
            int mm = tj >> 7, t = tj & 127;
            int tr = (t >> 4) << 5, tc = (t & 15) << 4;
            if (mm < nvec) {
                const float* As = mm ? (out + (size_t)(32 * mm - 1) * DD) : z0;
                size_t lda = mm ? LDT : (size_t)DD;
                gtile_compute(As, lda, W, DD, nullptr, 0.f, 0, 0, Af, Bf, tr, tc,
                              lane, acc);
                epi_v(out, Zb, nvec + mm, tr, tc, lane, acc);
            } else {
                gtile_compute(W, DD, W, DD, nullptr, 0.f, 0, 0, Af, Bf, tr, tc,
                              lane, acc);
                epi_plain(Wtab + (size_t)s * MATF, DD, tr, tc, lane, acc, 0);
            }
        }
        if (s < 3) gridbar(cnt, 8 + s);
    }
}

// ---------------- batched bf16 MFMA fill (proven r6) ------------------------
// 497 jobs; i = min(bz/31,15), j = bz - i*31 + 1. out[:, 32i+j-1, :] = Zb[i]@M_j
__global__ void __launch_bounds__(256)
fill_kernel(const unsigned short* __restrict__ Zb,
            const unsigned short* __restrict__ MTb,
            float* __restrict__ out) {
    __shared__ __align__(16) char pool[65536];
    const int bz = blockIdx.z;
    const int i = (bz >= 465) ? 15 : bz / 31;
    const int j = bz - i * 31 + 1;
    const int t = i * 32 + j - 1;
    const unsigned short* Zt = Zb + (size_t)i * MATF;
    const unsigned short* MT = MTb + (size_t)(j - 1) * MATF;

    const int tid = threadIdx.x;
    const int lane = tid & 63, wid = tid >> 6;
    const int rowBase = blockIdx.y * 128, colBase = blockIdx.x * 128;
    const int wr = (wid >> 1) * 64, wc = (wid & 1) * 64;

    int rowq[4], skq[4], ldsb[4];
#pragma unroll
    for (int q = 0; q < 4; ++q) {
        int c = q * 256 + wid * 64 + lane;
        int row = c >> 3;
        rowq[q] = row;
        skq[q] = ((c ^ (row & 7)) & 7) << 3;
        ldsb[q] = (q * 256 + wid * 64) << 4;
    }

    f32x4 acc[4][4];
#pragma unroll
    for (int a = 0; a < 4; ++a)
#pragma unroll
        for (int b = 0; b < 4; ++b) acc[a][b] = (f32x4){0.f, 0.f, 0.f, 0.f};

    auto stage = [&](int buf, int k0) {
        char* ab = pool + buf * 16384;
        char* bb = pool + 32768 + buf * 16384;
#pragma unroll
        for (int q = 0; q < 4; ++q) {
            GLD16(Zt + (size_t)(rowBase + rowq[q]) * DD + k0 + skq[q], ab + ldsb[q]);
            GLD16(MT + (size_t)(colBase + rowq[q]) * DD + k0 + skq[q], bb + ldsb[q]);
        }
    };

    stage(0, 0);
    __syncthreads();

    int cur = 0;
    for (int r = 0; r < 4; ++r) {
        if (r < 3) stage(cur ^ 1, (r + 1) * 64);
        const char* asb = pool + cur * 16384;
        const char* bsb = pool + 32768 + cur * 16384;
#pragma unroll
        for (int ks = 0; ks < 2; ++ks) {
            bf16x8 af[4], bg[4];
            const int kk = ks * 32 + (lane >> 4) * 8;
#pragma unroll
            for (int f = 0; f < 4; ++f) {
                int rr = wr + f * 16 + (lane & 15);
                af[f] = *(const bf16x8*)(asb + ((rr * 128 + kk * 2) ^ ((rr & 7) << 4)));
                int cc = wc + f * 16 + (lane & 15);
                bg[f] = *(const bf16x8*)(bsb + ((cc * 128 + kk * 2) ^ ((cc & 7) << 4)));
            }
#pragma unroll
            for (int fr = 0; fr < 4; ++fr)
#pragma unroll
                for (int fc = 0; fc < 4; ++fc)
                    acc[fr][fc] = __builtin_amdgcn_mfma_f32_16x16x32_bf16(
                        af[fr], bg[fc], acc[fr][fc], 0, 0, 0);
        }
        __syncthreads();
        cur ^= 1;
    }

    float* Cs = (float*)pool;
#pragma unroll
    for (int fr = 0; fr < 4; ++fr) {
#pragma unroll
        for (int fc = 0; fc < 4; ++fc) {
            int ccol = wc + fc * 16 + (lane & 15);
#pragma unroll
            for (int ii = 0; ii < 4; ++ii) {
                int r = wr + fr * 16 + ((lane >> 4) << 2) + ii;
                int csw = ccol ^ (((r >> 2) & 1) << 4);
                Cs[r * 128 + csw] = acc[fr][fc][ii];
            }
        }
    }
    __syncthreads();
    float* C = out + (size_t)t * DD;
#pragma unroll
    for (int it = 0; it < 16; ++it) {
        int chunk = it * 256 + tid;
        int row = chunk >> 5;
        int c4 = (chunk & 31) << 2;
        int csw = c4 ^ (((row >> 2) & 1) << 4);
        float4 v = *(const float4*)(Cs + row * 128 + csw);
        *(float4*)(C + (size_t)(rowBase + row) * LDT + colBase + c4) = v;
    }
}

// ---------------- fallback (tiny ws): proven g32 chain ----------------------
__global__ void prep_kernel(const float* __restrict__ K,
                            const float* __restrict__ log_dt,
                            float* __restrict__ A) {
    int idx = blockIdx.x * blockDim.x + threadIdx.x;
    A[idx] = 0.5f * expf(log_dt[0]) * K[idx];
}

__device__ __forceinline__ void g32_core(const float* Ab, int lda, const float* Bb,
                                         int ldb, int rowBase, int colBase,
                                         float acc[2][2]) {
    __shared__ __align__(16) float As[64 * 38];
    __shared__ __align__(16) float Bs[64 * 40];
    const int tid = threadIdx.x;
    const int tx = tid & 15, ty = tid >> 4;
    const int am = tid >> 4;
    const int ak = (tid & 15) << 2;
    const int bk = tid >> 3;
    const int bn = (tid & 7) << 2;
    acc[0][0] = acc[0][1] = acc[1][0] = acc[1][1] = 0.f;
    float4 pa0 = *(const float4*)(Ab + (size_t)(rowBase + am) * lda + ak);
    float4 pa1 = *(const float4*)(Ab + (size_t)(rowBase + am + 16) * lda + ak);
    float4 pb0 = *(const float4*)(Bb + (size_t)bk * ldb + colBase + bn);
    float4 pb1 = *(const float4*)(Bb + (size_t)(bk + 32) * ldb + colBase + bn);
    for (int k0 = 0; k0 < DD; k0 += 64) {
        As[(ak + 0) * 38 + am] = pa0.x;
        As[(ak + 1) * 38 + am] = pa0.y;
        As[(ak + 2) * 38 + am] = pa0.z;
        As[(ak + 3) * 38 + am] = pa0.w;
        As[(ak + 0) * 38 + am + 16] = pa1.x;
        As[(ak + 1) * 38 + am + 16] = pa1.y;
        As[(ak + 2) * 38 + am + 16] = pa1.z;
        As[(ak + 3) * 38 + am + 16] = pa1.w;
        *(float4*)(&Bs[bk * 40 + bn]) = pb0;
        *(float4*)(&Bs[(bk + 32) * 40 + bn]) = pb1;
        __syncthreads();
        if (k0 + 64 < DD) {
            pa0 = *(const float4*)(Ab + (size_t)(rowBase + am) * lda + k0 + 64 + ak);
            pa1 = *(const float4*)(Ab + (size_t)(rowBase + am + 16) * lda + k0 + 64 + ak);
            pb0 = *(const float4*)(Bb + (size_t)(bk + k0 + 64) * ldb + colBase + bn);
            pb1 = *(const float4*)(Bb + (size_t)(bk + 32 + k0 + 64) * ldb + colBase + bn);
        }
#pragma unroll
        for (int kk = 0; kk < 64; ++kk) {
            float2 a2 = *(const float2*)(&As[kk * 38 + (ty << 1)]);
            float2 b2 = *(const float2*)(&Bs[kk * 40 + (tx << 1)]);
            acc[0][0] = fmaf(a2.x, b2.x, acc[0][0]);
            acc[0][1] = fmaf(a2.x, b2.y, acc[0][1]);
            acc[1][0] = fmaf(a2.y, b2.x, acc[1][0]);
            acc[1][1] = fmaf(a2.y, b2.y, acc[1][1]);
        }
        __syncthreads();
    }
}

template <int EPI>
__global__ void __launch_bounds__(256)
g32_kernel(const float* A, const float* B, float* C, const float* E, float* C2,
           int lda, int ldb, int ldc, long long sA, long long sB, long long sC) {
    float acc[2][2];
    const int rowBase = blockIdx.y << 5, colBase = blockIdx.x << 5;
    g32_core(A + blockIdx.z * sA, lda, B + blockIdx.z * sB, ldb, rowBase, colBase, acc);
    float* Cb = C + blockIdx.z * sC;
    const int r0 = rowBase + ((threadIdx.x >> 4) << 1);
    const int c0 = colBase + ((threadIdx.x & 15) << 1);
#pragma unroll
    for (int i = 0; i < 2; ++i) {
        int r = r0 + i;
        float2 v;
        if (EPI == 2) {
            float e0 = E[(size_t)r * DD + c0], e1 = E[(size_t)r * DD + c0 + 1];
            v.x = acc[i][0] + 2.f * e0 + (r == c0 ? 1.f : 0.f);
            v.y = acc[i][1] + 2.f * e1 + (r == c0 + 1 ? 1.f : 0.f);
        } else {
            v.x = acc[i][0];
            v.y = acc[i][1];
        }
        *(float2*)(Cb + (size_t)r * ldc + c0) = v;
        if (EPI == 1) {
            float e0 = E[(size_t)r * DD + c0], e1 = E[(size_t)r * DD + c0 + 1];
            float2 w;
            w.x = 2.f * acc[i][0] + 2.f * e0 + (r == c0 ? 2.f : 0.f);
            w.y = 2.f * acc[i][1] + 2.f * e1 + (r == c0 + 1 ? 2.f : 0.f);
            *(float2*)(C2 + (size_t)r * DD + c0) = w;
        }
    }
}

// ---------------- launch ----------------------------------------------------
extern "C" void kernel_launch(void* const* d_in, const int* in_sizes, int n_in,
                              void* d_out, int out_size, void* d_ws, size_t ws_size,
                              hipStream_t stream) {
    const float* z0 = (const float*)d_in[0];
    const float* Kmat = (const float*)d_in[1];
    const float* log_dt = (const float*)d_in[2];
    float* out = (float*)d_out;

    dim3 blk(256);

    // ws: Mtab[32] | Wtab[3] | Pmat | MTb[32] bf16 | Zb[16] bf16 | cnt
    float* Mtab = (float*)d_ws;
    float* Wtab = Mtab + (size_t)32 * MATF;
    float* Pmat = Wtab + (size_t)3 * MATF;
    unsigned short* MTb = (unsigned short*)(Pmat + MATF);
    unsigned short* Zb = MTb + (size_t)32 * MATF;
    unsigned* cnt = (unsigned*)(Zb + (size_t)16 * MATF);
    const size_t need = (size_t)36 * MATF * 4 + (size_t)48 * MATF * 2 + 256;

    if (ws_size >= need) {
        binit_kernel<<<1, 64, 0, stream>>>(cnt);
        tabs_kernel<<<NBLK, blk, 0, stream>>>(z0, Kmat, log_dt, out, Mtab, Wtab,
                                              Pmat, MTb, Zb, cnt);
        fill_kernel<<<dim3(2, 2, 497), blk, 0, stream>>>(Zb, MTb, out);
        return;
    }

    // Minimal fallback (tiny ws): Kd then 512 chained GEMMs (f32, proven core).
    float* A = (float*)d_ws;
    float* A2 = A + MATF;
    float* Bop = A2 + MATF;
    float* Kd = Bop + MATF;
    prep_kernel<<<MATF / 256, blk, 0, stream>>>(Kmat, log_dt, A);
    dim3 g(8, 8, 1);
    g32_kernel<1><<<g, blk, 0, stream>>>(A, A, A2, A, Bop, DD, DD, DD, 0, 0, 0);
    g32_kernel<2><<<g, blk, 0, stream>>>(A2, Bop, Kd, A, (float*)0, DD, DD, DD, 0, 0, 0);
    for (int t = 0; t < TT; ++t) {
        const float* Ain = (t == 0) ? z0 : out + (size_t)(t - 1) * DD;
        int lda = (t == 0) ? DD : (int)LDT;
        g32_kernel<0><<<g, blk, 0, stream>>>(Ain, Kd, out + (size_t)t * DD,
                                             (const float*)0, (float*)0,
                                             lda, DD, (int)LDT, 0, 0, 0);
    }
}

// Round 8
// 146.917 us; speedup vs baseline: 2.2021x; 2.2021x over previous
//
#include <hip/hip_runtime.h>

// Koopman bilinear rollout: preds[b,t,d] = (z0 @ Kd^{t+1})[b,d], D=B=256, T=512.
// Kd = (I-A)^-1(I+A), A=0.5*dt*K -> order-4 Neumann (2 launches, proven r2-r6).
// M_j=Kd^j (j=1..32, 5 doubling launches), checkpoint scan (4 batched levels),
// one batched bf16-MFMA fill for the remaining 497 timesteps.
// r8: prep folded into N1, mtrans folded into table-producer epilogues
// (12 launches total); fill single-buffered 32KB LDS (4 blocks/CU).
// DEAD ENDS (do not retry): persistent kernel + grid barrier -- r5 acquire-poll
// 392us, r7 relaxed-poll+fence 289us; cache-maintenance storm either way.

#define DD 256
#define TT 512
#define MATF (DD * DD)
#define LDT ((size_t)TT * (size_t)DD)

typedef __attribute__((ext_vector_type(8))) short bf16x8;
typedef __attribute__((ext_vector_type(4))) float f32x4;

#define GLD16(g, l)                                                  \
    __builtin_amdgcn_global_load_lds(                                \
        (const __attribute__((address_space(1))) void*)(g),          \
        (__attribute__((address_space(3))) void*)(l), 16, 0, 0)

static __device__ __forceinline__ unsigned short f2bf(float f) {
    unsigned int u = __float_as_uint(f);
    u += 0x7fffu + ((u >> 16) & 1u);
    return (unsigned short)(u >> 16);
}
static __device__ __forceinline__ unsigned pack2bf(float a, float b) {
    return (unsigned)f2bf(a) | ((unsigned)f2bf(b) << 16);
}

// ---- 32x32-tile f32 GEMM core: 256 threads, K=256, K_BLK=64, reg prefetch ----
// (byte-identical to the proven r3-r6 core)
__device__ __forceinline__ void g32_core(const float* __restrict__ Ab, int lda,
                                         const float* __restrict__ Bb, int ldb,
                                         int rowBase, int colBase, float acc[2][2]) {
    __shared__ __align__(16) float As[64 * 38];
    __shared__ __align__(16) float Bs[64 * 40];
    const int tid = threadIdx.x;
    const int tx = tid & 15, ty = tid >> 4;
    const int am = tid >> 4;
    const int ak = (tid & 15) << 2;
    const int bk = tid >> 3;
    const int bn = (tid & 7) << 2;

    acc[0][0] = acc[0][1] = acc[1][0] = acc[1][1] = 0.f;

    float4 pa0 = *(const float4*)(Ab + (size_t)(rowBase + am) * lda + ak);
    float4 pa1 = *(const float4*)(Ab + (size_t)(rowBase + am + 16) * lda + ak);
    float4 pb0 = *(const float4*)(Bb + (size_t)bk * ldb + colBase + bn);
    float4 pb1 = *(const float4*)(Bb + (size_t)(bk + 32) * ldb + colBase + bn);

    for (int k0 = 0; k0 < DD; k0 += 64) {
        As[(ak + 0) * 38 + am] = pa0.x;
        As[(ak + 1) * 38 + am] = pa0.y;
        As[(ak + 2) * 38 + am] = pa0.z;
        As[(ak + 3) * 38 + am] = pa0.w;
        As[(ak + 0) * 38 + am + 16] = pa1.x;
        As[(ak + 1) * 38 + am + 16] = pa1.y;
        As[(ak + 2) * 38 + am + 16] = pa1.z;
        As[(ak + 3) * 38 + am + 16] = pa1.w;
        *(float4*)(&Bs[bk * 40 + bn]) = pb0;
        *(float4*)(&Bs[(bk + 32) * 40 + bn]) = pb1;
        __syncthreads();
        if (k0 + 64 < DD) {
            pa0 = *(const float4*)(Ab + (size_t)(rowBase + am) * lda + k0 + 64 + ak);
            pa1 = *(const float4*)(Ab + (size_t)(rowBase + am + 16) * lda + k0 + 64 + ak);
            pb0 = *(const float4*)(Bb + (size_t)(bk + k0 + 64) * ldb + colBase + bn);
            pb1 = *(const float4*)(Bb + (size_t)(bk + 32 + k0 + 64) * ldb + colBase + bn);
        }
#pragma unroll
        for (int kk = 0; kk < 64; ++kk) {
            float2 a2 = *(const float2*)(&As[kk * 38 + (ty << 1)]);
            float2 b2 = *(const float2*)(&Bs[kk * 40 + (tx << 1)]);
            acc[0][0] = fmaf(a2.x, b2.x, acc[0][0]);
            acc[0][1] = fmaf(a2.x, b2.y, acc[0][1]);
            acc[1][0] = fmaf(a2.y, b2.x, acc[1][0]);
            acc[1][1] = fmaf(a2.y, b2.y, acc[1][1]);
        }
        __syncthreads();
    }
}

// N1: acc = K@K. A2 = cs^2*acc ; Bop = 2I + 2cs*K + 2cs^2*acc ; Zb0 = bf16(z0)
__global__ void __launch_bounds__(256)
n1_kernel(const float* __restrict__ K, const float* __restrict__ log_dt,
          const float* __restrict__ z0, float* __restrict__ A2,
          float* __restrict__ Bop, unsigned short* __restrict__ Zb0) {
    const float cs = 0.5f * expf(log_dt[0]);
    // fold prep: convert 4 z0 elements per thread (64 blk * 256 thr * 4 = 65536)
    {
        int b = ((blockIdx.y * 8 + blockIdx.x) * 256 + threadIdx.x) * 4;
        uint2 w;
        w.x = pack2bf(z0[b], z0[b + 1]);
        w.y = pack2bf(z0[b + 2], z0[b + 3]);
        *(uint2*)(Zb0 + b) = w;
    }
    float acc[2][2];
    const int rowBase = blockIdx.y << 5, colBase = blockIdx.x << 5;
    g32_core(K, DD, K, DD, rowBase, colBase, acc);
    const float cs2 = cs * cs;
    const int r0 = rowBase + ((threadIdx.x >> 4) << 1);
    const int c0 = colBase + ((threadIdx.x & 15) << 1);
#pragma unroll
    for (int i = 0; i < 2; ++i) {
        int r = r0 + i;
        float e0 = K[(size_t)r * DD + c0], e1 = K[(size_t)r * DD + c0 + 1];
        float p0 = cs2 * acc[i][0], p1 = cs2 * acc[i][1];
        *(float2*)(A2 + (size_t)r * DD + c0) = (float2){p0, p1};
        float2 w;
        w.x = 2.f * p0 + 2.f * cs * e0 + (r == c0 ? 2.f : 0.f);
        w.y = 2.f * p1 + 2.f * cs * e1 + (r == c0 + 1 ? 2.f : 0.f);
        *(float2*)(Bop + (size_t)r * DD + c0) = w;
    }
}

// N2: Kd = A2@Bop + I + 2cs*K -> Mtab[0], and MTb[0][c][k] = bf16(Kd[k][c])
__global__ void __launch_bounds__(256)
n2_kernel(const float* __restrict__ A2, const float* __restrict__ Bop,
          const float* __restrict__ K, const float* __restrict__ log_dt,
          float* __restrict__ Kd, unsigned short* __restrict__ MT0) {
    const float cs = 0.5f * expf(log_dt[0]);
    float acc[2][2];
    const int rowBase = blockIdx.y << 5, colBase = blockIdx.x << 5;
    g32_core(A2, DD, Bop, DD, rowBase, colBase, acc);
    const int r0 = rowBase + ((threadIdx.x >> 4) << 1);
    const int c0 = colBase + ((threadIdx.x & 15) << 1);
    float v[2][2];
#pragma unroll
    for (int i = 0; i < 2; ++i) {
        int r = r0 + i;
        float e0 = K[(size_t)r * DD + c0], e1 = K[(size_t)r * DD + c0 + 1];
        v[i][0] = acc[i][0] + 2.f * cs * e0 + (r == c0 ? 1.f : 0.f);
        v[i][1] = acc[i][1] + 2.f * cs * e1 + (r == c0 + 1 ? 1.f : 0.f);
        *(float2*)(Kd + (size_t)r * DD + c0) = (float2){v[i][0], v[i][1]};
    }
    // transposed bf16: MT[c][r0..r0+1]
    *(unsigned*)(MT0 + (size_t)c0 * DD + r0) = pack2bf(v[0][0], v[1][0]);
    *(unsigned*)(MT0 + (size_t)(c0 + 1) * DD + r0) = pack2bf(v[0][1], v[1][1]);
}

// Doubling (batched over mm): M_{p+mm+1} = M_{mm+1} @ M_p, + transposed bf16.
__global__ void __launch_bounds__(256)
dbl_kernel(float* __restrict__ Mtab, unsigned short* __restrict__ MTb, int p) {
    const int mm = blockIdx.z;
    float acc[2][2];
    const int rowBase = blockIdx.y << 5, colBase = blockIdx.x << 5;
    g32_core(Mtab + (size_t)mm * MATF, DD, Mtab + (size_t)(p - 1) * MATF, DD,
             rowBase, colBase, acc);
    float* Cm = Mtab + (size_t)(p + mm) * MATF;
    unsigned short* MTm = MTb + (size_t)(p + mm) * MATF;
    const int r0 = rowBase + ((threadIdx.x >> 4) << 1);
    const int c0 = colBase + ((threadIdx.x & 15) << 1);
#pragma unroll
    for (int i = 0; i < 2; ++i) {
        int r = r0 + i;
        *(float2*)(Cm + (size_t)r * DD + c0) = (float2){acc[i][0], acc[i][1]};
    }
    *(unsigned*)(MTm + (size_t)c0 * DD + r0) = pack2bf(acc[0][0], acc[1][0]);
    *(unsigned*)(MTm + (size_t)(c0 + 1) * DD + r0) = pack2bf(acc[0][1], acc[1][1]);
}

// Checkpoint scan level s (batched, proven r6): jobs mm < 2^s are Z-jobs
//   Z_{2^s+mm} = Z_mm @ W_{2^s} (Z_0 = z0) -> f32 out[:,32*dst-1,:] + bf16 Zb[dst]
// job mm == 2^s (s<3) squares W: Wtab[s] = W_{2^s} @ W_{2^s}. W_1 = Mtab[31].
__global__ void __launch_bounds__(256)
scan_kernel(const float* __restrict__ z0, float* __restrict__ out,
            const float* __restrict__ M32, float* __restrict__ Wtab,
            unsigned short* __restrict__ Zb, int s) {
    const int nvec = 1 << s;
    const int mm = blockIdx.z;
    const float* W = (s == 0) ? M32 : Wtab + (size_t)(s - 1) * MATF;
    float acc[2][2];
    const int rowBase = blockIdx.y << 5, colBase = blockIdx.x << 5;
    const int r0 = rowBase + ((threadIdx.x >> 4) << 1);
    const int c0 = colBase + ((threadIdx.x & 15) << 1);
    if (mm < nvec) {
        const float* Asrc = mm ? out + (size_t)(32 * mm - 1) * DD : z0;
        int lda = mm ? (int)LDT : DD;
        g32_core(Asrc, lda, W, DD, rowBase, colBase, acc);
        const int dst = nvec + mm;  // 1..15
        float* Of = out + (size_t)(32 * dst - 1) * DD;
        unsigned short* Zo = Zb + (size_t)dst * MATF;
#pragma unroll
        for (int ii = 0; ii < 2; ++ii) {
            int r = r0 + ii;
            float2 v = {acc[ii][0], acc[ii][1]};
            *(float2*)(Of + (size_t)r * LDT + c0) = v;
            *(unsigned*)(Zo + (size_t)r * DD + c0) = pack2bf(v.x, v.y);
        }
    } else {
        g32_core(W, DD, W, DD, rowBase, colBase, acc);
        float* Cb = Wtab + (size_t)s * MATF;
#pragma unroll
        for (int ii = 0; ii < 2; ++ii) {
            int r = r0 + ii;
            *(float2*)(Cb + (size_t)r * DD + c0) = (float2){acc[ii][0], acc[ii][1]};
        }
    }
}

// Batched bf16 MFMA fill: 497 jobs; i = min(bz/31,15), j = bz - i*31 + 1.
// out[:, 32i+j-1, :] = Zb[i] @ M_j. 128x128 tile, 4 waves.
// r8: single-buffered 32KB LDS (4 blocks/CU) + two-pass LDS-staged C write.
__global__ void __launch_bounds__(256)
fill_kernel(const unsigned short* __restrict__ Zb,
            const unsigned short* __restrict__ MTb,
            float* __restrict__ out) {
    __shared__ __align__(16) char pool[32768];  // A 16KB | B 16KB ; C half-tile reuse
    const int bz = blockIdx.z;
    const int i = (bz >= 465) ? 15 : bz / 31;
    const int j = bz - i * 31 + 1;
    const int t = i * 32 + j - 1;
    const unsigned short* Zt = Zb + (size_t)i * MATF;         // [row][k]
    const unsigned short* MT = MTb + (size_t)(j - 1) * MATF;  // [col][k]

    const int tid = threadIdx.x;
    const int lane = tid & 63, wid = tid >> 6;
    const int rowBase = blockIdx.y * 128, colBase = blockIdx.x * 128;
    const int wr = (wid >> 1) * 64, wc = (wid & 1) * 64;

    int rowq[4], skq[4], ldsb[4];
#pragma unroll
    for (int q = 0; q < 4; ++q) {
        int c = q * 256 + wid * 64 + lane;
        int row = c >> 3;
        rowq[q] = row;
        skq[q] = ((c ^ (row & 7)) & 7) << 3;  // pre-swizzled src k-offset
        ldsb[q] = (q * 256 + wid * 64) << 4;  // wave-uniform LDS byte base
    }

    f32x4 acc[4][4];
#pragma unroll
    for (int a = 0; a < 4; ++a)
#pragma unroll
        for (int b = 0; b < 4; ++b) acc[a][b] = (f32x4){0.f, 0.f, 0.f, 0.f};

    auto stage = [&](int k0) {
#pragma unroll
        for (int q = 0; q < 4; ++q) {
            GLD16(Zt + (size_t)(rowBase + rowq[q]) * DD + k0 + skq[q], pool + ldsb[q]);
            GLD16(MT + (size_t)(colBase + rowq[q]) * DD + k0 + skq[q],
                  pool + 16384 + ldsb[q]);
        }
    };

    stage(0);
    for (int r = 0; r < 4; ++r) {
        __syncthreads();  // drains vmcnt -> staged data visible
        const char* asb = pool;
        const char* bsb = pool + 16384;
#pragma unroll
        for (int ks = 0; ks < 2; ++ks) {
            bf16x8 af[4], bg[4];
            const int kk = ks * 32 + (lane >> 4) * 8;
#pragma unroll
            for (int f = 0; f < 4; ++f) {
                int rr = wr + f * 16 + (lane & 15);
                af[f] = *(const bf16x8*)(asb + ((rr * 128 + kk * 2) ^ ((rr & 7) << 4)));
                int cc = wc + f * 16 + (lane & 15);
                bg[f] = *(const bf16x8*)(bsb + ((cc * 128 + kk * 2) ^ ((cc & 7) << 4)));
            }
#pragma unroll
            for (int fr = 0; fr < 4; ++fr)
#pragma unroll
                for (int fc = 0; fc < 4; ++fc)
                    acc[fr][fc] = __builtin_amdgcn_mfma_f32_16x16x32_bf16(
                        af[fr], bg[fc], acc[fr][fc], 0, 0, 0);
        }
        __syncthreads();  // all waves done reading before overwrite
        if (r < 3) stage((r + 1) * 64);
    }

    // C epilogue in two 64-row half-tile passes through 32KB LDS
    float* Cs = (float*)pool;  // 64 x 128 f32 = 32KB
    float* C = out + (size_t)t * DD;
#pragma unroll
    for (int hp = 0; hp < 2; ++hp) {
        __syncthreads();
        if (wr == hp * 64) {
#pragma unroll
            for (int fr = 0; fr < 4; ++fr) {
#pragma unroll
                for (int fc = 0; fc < 4; ++fc) {
                    int ccol = wc + fc * 16 + (lane & 15);
#pragma unroll
                    for (int ii = 0; ii < 4; ++ii) {
                        int lr = fr * 16 + ((lane >> 4) << 2) + ii;  // 0..63
                        int csw = ccol ^ (((lr >> 2) & 1) << 4);
                        Cs[lr * 128 + csw] = acc[fr][fc][ii];
                    }
                }
            }
        }
        __syncthreads();
#pragma unroll
        for (int it = 0; it < 8; ++it) {
            int chunk = it * 256 + tid;  // 0..2047
            int row = chunk >> 5;        // 0..63
            int c4 = (chunk & 31) << 2;
            int csw = c4 ^ (((row >> 2) & 1) << 4);
            float4 v = *(const float4*)(Cs + row * 128 + csw);
            *(float4*)(C + (size_t)(rowBase + hp * 64 + row) * LDT + colBase + c4) = v;
        }
    }
}

// ---------------- fallback (tiny ws): proven g32 chain ----------------------
__global__ void prep_kernel(const float* __restrict__ K,
                            const float* __restrict__ log_dt,
                            float* __restrict__ A) {
    int idx = blockIdx.x * blockDim.x + threadIdx.x;
    A[idx] = 0.5f * expf(log_dt[0]) * K[idx];
}

template <int EPI>
__global__ void __launch_bounds__(256)
g32_kernel(const float* A, const float* B, float* C, const float* E, float* C2,
           int lda, int ldb, int ldc, long long sA, long long sB, long long sC) {
    float acc[2][2];
    const int rowBase = blockIdx.y << 5, colBase = blockIdx.x << 5;
    g32_core(A + blockIdx.z * sA, lda, B + blockIdx.z * sB, ldb, rowBase, colBase, acc);
    float* Cb = C + blockIdx.z * sC;
    const int r0 = rowBase + ((threadIdx.x >> 4) << 1);
    const int c0 = colBase + ((threadIdx.x & 15) << 1);
#pragma unroll
    for (int i = 0; i < 2; ++i) {
        int r = r0 + i;
        float2 v;
        if (EPI == 2) {
            float e0 = E[(size_t)r * DD + c0], e1 = E[(size_t)r * DD + c0 + 1];
            v.x = acc[i][0] + 2.f * e0 + (r == c0 ? 1.f : 0.f);
            v.y = acc[i][1] + 2.f * e1 + (r == c0 + 1 ? 1.f : 0.f);
        } else {
            v.x = acc[i][0];
            v.y = acc[i][1];
        }
        *(float2*)(Cb + (size_t)r * ldc + c0) = v;
        if (EPI == 1) {
            float e0 = E[(size_t)r * DD + c0], e1 = E[(size_t)r * DD + c0 + 1];
            float2 w;
            w.x = 2.f * acc[i][0] + 2.f * e0 + (r == c0 ? 2.f : 0.f);
            w.y = 2.f * acc[i][1] + 2.f * e1 + (r == c0 + 1 ? 2.f : 0.f);
            *(float2*)(C2 + (size_t)r * DD + c0) = w;
        }
    }
}

// ---------------- launch ----------------------------------------------------
extern "C" void kernel_launch(void* const* d_in, const int* in_sizes, int n_in,
                              void* d_out, int out_size, void* d_ws, size_t ws_size,
                              hipStream_t stream) {
    const float* z0 = (const float*)d_in[0];
    const float* Kmat = (const float*)d_in[1];
    const float* log_dt = (const float*)d_in[2];
    float* out = (float*)d_out;

    dim3 blk(256);

    // ws: A2 | Bop | Mtab[32] | Wtab[3] f32 | MTb[32] bf16 | Zb[16] bf16
    float* A2 = (float*)d_ws;
    float* Bop = A2 + MATF;
    float* Mtab = Bop + MATF;
    float* Wtab = Mtab + (size_t)32 * MATF;
    unsigned short* MTb = (unsigned short*)(Wtab + (size_t)3 * MATF);
    unsigned short* Zb = MTb + (size_t)32 * MATF;
    const size_t need = (size_t)37 * MATF * 4 + (size_t)48 * MATF * 2;

    if (ws_size >= need) {
        dim3 g(8, 8, 1);
        // Neumann order-4 (2 launches; prep + z0-conversion folded into N1)
        n1_kernel<<<g, blk, 0, stream>>>(Kmat, log_dt, z0, A2, Bop, Zb);
        n2_kernel<<<g, blk, 0, stream>>>(A2, Bop, Kmat, log_dt, Mtab, MTb);

        // M powers (bf16-T written in epilogue): M_1..M_32
        for (int p = 1; p < 32; p <<= 1)
            dbl_kernel<<<dim3(8, 8, p), blk, 0, stream>>>(Mtab, MTb, p);

        // checkpoint scan: 4 batched levels (Z-jobs + W-squaring per level)
        const int njobs[4] = {2, 3, 5, 8};
        for (int s = 0; s < 4; ++s)
            scan_kernel<<<dim3(8, 8, njobs[s]), blk, 0, stream>>>(
                z0, out, Mtab + (size_t)31 * MATF, Wtab, Zb, s);

        // All 497 remaining timesteps in one batched MFMA launch
        fill_kernel<<<dim3(2, 2, 497), blk, 0, stream>>>(Zb, MTb, out);
        return;
    }

    // Minimal fallback (tiny ws): Kd then 512 chained GEMMs (f32, proven core).
    float* A = (float*)d_ws;
    float* A2f = A + MATF;
    float* Bopf = A2f + MATF;
    float* Kd = Bopf + MATF;
    prep_kernel<<<MATF / 256, blk, 0, stream>>>(Kmat, log_dt, A);
    dim3 g(8, 8, 1);
    g32_kernel<1><<<g, blk, 0, stream>>>(A, A, A2f, A, Bopf, DD, DD, DD, 0, 0, 0);
    g32_kernel<2><<<g, blk, 0, stream>>>(A2f, Bopf, Kd, A, (float*)0, DD, DD, DD, 0, 0, 0);
    for (int t = 0; t < TT; ++t) {
        const float* Ain = (t == 0) ? z0 : out + (size_t)(t - 1) * DD;
        int lda = (t == 0) ? DD : (int)LDT;
        g32_kernel<0><<<g, blk, 0, stream>>>(Ain, Kd, out + (size_t)t * DD,
                                             (const float*)0, (float*)0,
                                             lda, DD, (int)LDT, 0, 0, 0);
    }
}

// Round 9
// 120.470 us; speedup vs baseline: 2.6855x; 1.2195x over previous
//
#include <hip/hip_runtime.h>

// Koopman bilinear rollout: preds[b,t,d] = (z0 @ Kd^{t+1})[b,d], D=B=256, T=512.
// Kd = (I-A)^-1(I+A), A=0.5*dt*K -> order-4 Neumann (2 launches, proven r2-r8).
// r9: M-table via binomial series in E = Kd - I (||E||~0.022):
//   E^2..E^6 in 3 GEMM stages, then ONE comb launch writes all
//   MTb[j][c][k]=bf16(M_j[k][c]) (j=1..32, trunc m<=6, err ~1e-5) + W1=M32 f32.
// Checkpoint scan (4 batched levels, proven r6) + one batched bf16-MFMA fill
// (proven r6/r8) for the remaining 497 timesteps. 11 launches total.
// DEAD ENDS (do not retry): persistent kernel + grid barrier -- r5 acquire-poll
// 392us, r7 relaxed-poll+fence 289us; cache-maintenance storm either way.

#define DD 256
#define TT 512
#define MATF (DD * DD)
#define LDT ((size_t)TT * (size_t)DD)

typedef __attribute__((ext_vector_type(8))) short bf16x8;
typedef __attribute__((ext_vector_type(4))) float f32x4;

#define GLD16(g, l)                                                  \
    __builtin_amdgcn_global_load_lds(                                \
        (const __attribute__((address_space(1))) void*)(g),          \
        (__attribute__((address_space(3))) void*)(l), 16, 0, 0)

static __device__ __forceinline__ unsigned short f2bf(float f) {
    unsigned int u = __float_as_uint(f);
    u += 0x7fffu + ((u >> 16) & 1u);
    return (unsigned short)(u >> 16);
}
static __device__ __forceinline__ unsigned pack2bf(float a, float b) {
    return (unsigned)f2bf(a) | ((unsigned)f2bf(b) << 16);
}

// ---- 32x32-tile f32 GEMM core: 256 threads, K=256, K_BLK=64, reg prefetch ----
// (byte-identical to the proven r3-r8 core)
__device__ __forceinline__ void g32_core(const float* __restrict__ Ab, int lda,
                                         const float* __restrict__ Bb, int ldb,
                                         int rowBase, int colBase, float acc[2][2]) {
    __shared__ __align__(16) float As[64 * 38];
    __shared__ __align__(16) float Bs[64 * 40];
    const int tid = threadIdx.x;
    const int tx = tid & 15, ty = tid >> 4;
    const int am = tid >> 4;
    const int ak = (tid & 15) << 2;
    const int bk = tid >> 3;
    const int bn = (tid & 7) << 2;

    acc[0][0] = acc[0][1] = acc[1][0] = acc[1][1] = 0.f;

    float4 pa0 = *(const float4*)(Ab + (size_t)(rowBase + am) * lda + ak);
    float4 pa1 = *(const float4*)(Ab + (size_t)(rowBase + am + 16) * lda + ak);
    float4 pb0 = *(const float4*)(Bb + (size_t)bk * ldb + colBase + bn);
    float4 pb1 = *(const float4*)(Bb + (size_t)(bk + 32) * ldb + colBase + bn);

    for (int k0 = 0; k0 < DD; k0 += 64) {
        As[(ak + 0) * 38 + am] = pa0.x;
        As[(ak + 1) * 38 + am] = pa0.y;
        As[(ak + 2) * 38 + am] = pa0.z;
        As[(ak + 3) * 38 + am] = pa0.w;
        As[(ak + 0) * 38 + am + 16] = pa1.x;
        As[(ak + 1) * 38 + am + 16] = pa1.y;
        As[(ak + 2) * 38 + am + 16] = pa1.z;
        As[(ak + 3) * 38 + am + 16] = pa1.w;
        *(float4*)(&Bs[bk * 40 + bn]) = pb0;
        *(float4*)(&Bs[(bk + 32) * 40 + bn]) = pb1;
        __syncthreads();
        if (k0 + 64 < DD) {
            pa0 = *(const float4*)(Ab + (size_t)(rowBase + am) * lda + k0 + 64 + ak);
            pa1 = *(const float4*)(Ab + (size_t)(rowBase + am + 16) * lda + k0 + 64 + ak);
            pb0 = *(const float4*)(Bb + (size_t)(bk + k0 + 64) * ldb + colBase + bn);
            pb1 = *(const float4*)(Bb + (size_t)(bk + 32 + k0 + 64) * ldb + colBase + bn);
        }
#pragma unroll
        for (int kk = 0; kk < 64; ++kk) {
            float2 a2 = *(const float2*)(&As[kk * 38 + (ty << 1)]);
            float2 b2 = *(const float2*)(&Bs[kk * 40 + (tx << 1)]);
            acc[0][0] = fmaf(a2.x, b2.x, acc[0][0]);
            acc[0][1] = fmaf(a2.x, b2.y, acc[0][1]);
            acc[1][0] = fmaf(a2.y, b2.x, acc[1][0]);
            acc[1][1] = fmaf(a2.y, b2.y, acc[1][1]);
        }
        __syncthreads();
    }
}

// N1: acc = K@K. A2 = cs^2*acc ; Bop = 2I + 2cs*K + 2cs^2*acc ; Zb0 = bf16(z0)
__global__ void __launch_bounds__(256)
n1_kernel(const float* __restrict__ K, const float* __restrict__ log_dt,
          const float* __restrict__ z0, float* __restrict__ A2,
          float* __restrict__ Bop, unsigned short* __restrict__ Zb0) {
    const float cs = 0.5f * expf(log_dt[0]);
    {
        int b = ((blockIdx.y * 8 + blockIdx.x) * 256 + threadIdx.x) * 4;
        uint2 w;
        w.x = pack2bf(z0[b], z0[b + 1]);
        w.y = pack2bf(z0[b + 2], z0[b + 3]);
        *(uint2*)(Zb0 + b) = w;
    }
    float acc[2][2];
    const int rowBase = blockIdx.y << 5, colBase = blockIdx.x << 5;
    g32_core(K, DD, K, DD, rowBase, colBase, acc);
    const float cs2 = cs * cs;
    const int r0 = rowBase + ((threadIdx.x >> 4) << 1);
    const int c0 = colBase + ((threadIdx.x & 15) << 1);
#pragma unroll
    for (int i = 0; i < 2; ++i) {
        int r = r0 + i;
        float e0 = K[(size_t)r * DD + c0], e1 = K[(size_t)r * DD + c0 + 1];
        float p0 = cs2 * acc[i][0], p1 = cs2 * acc[i][1];
        *(float2*)(A2 + (size_t)r * DD + c0) = (float2){p0, p1};
        float2 w;
        w.x = 2.f * p0 + 2.f * cs * e0 + (r == c0 ? 2.f : 0.f);
        w.y = 2.f * p1 + 2.f * cs * e1 + (r == c0 + 1 ? 2.f : 0.f);
        *(float2*)(Bop + (size_t)r * DD + c0) = w;
    }
}

// N2: E = Kd - I = A2@Bop + 2cs*K   (f32, natural layout)
__global__ void __launch_bounds__(256)
n2_kernel(const float* __restrict__ A2, const float* __restrict__ Bop,
          const float* __restrict__ K, const float* __restrict__ log_dt,
          float* __restrict__ E) {
    const float cs = 0.5f * expf(log_dt[0]);
    float acc[2][2];
    const int rowBase = blockIdx.y << 5, colBase = blockIdx.x << 5;
    g32_core(A2, DD, Bop, DD, rowBase, colBase, acc);
    const int r0 = rowBase + ((threadIdx.x >> 4) << 1);
    const int c0 = colBase + ((threadIdx.x & 15) << 1);
#pragma unroll
    for (int i = 0; i < 2; ++i) {
        int r = r0 + i;
        float e0 = K[(size_t)r * DD + c0], e1 = K[(size_t)r * DD + c0 + 1];
        float2 v;
        v.x = acc[i][0] + 2.f * cs * e0;
        v.y = acc[i][1] + 2.f * cs * e1;
        *(float2*)(E + (size_t)r * DD + c0) = v;
    }
}

// Generic batched 256^3 f32 GEMM (plain epilogue) for E-power stages.
__global__ void __launch_bounds__(256)
gpow_kernel(const float* __restrict__ A, const float* __restrict__ B,
            float* __restrict__ C, long long sA, long long sB, long long sC) {
    float acc[2][2];
    const int rowBase = blockIdx.y << 5, colBase = blockIdx.x << 5;
    g32_core(A + blockIdx.z * sA, DD, B + blockIdx.z * sB, DD, rowBase, colBase, acc);
    float* Cb = C + blockIdx.z * sC;
    const int r0 = rowBase + ((threadIdx.x >> 4) << 1);
    const int c0 = colBase + ((threadIdx.x & 15) << 1);
#pragma unroll
    for (int i = 0; i < 2; ++i) {
        int r = r0 + i;
        *(float2*)(Cb + (size_t)r * DD + c0) = (float2){acc[i][0], acc[i][1]};
    }
}

// comb: M_j = I + sum_{m=1}^{6} C(j,m) E^m, j=1..32.
// Writes MTb[j-1][c][k] = bf16(M_j[k][c]) and W1[k][c] = f32(M_32[k][c]).
// Grid 8x8 (32x32 tiles of (k,c)); 256 threads.
__global__ void __launch_bounds__(256)
comb_kernel(const float* __restrict__ Epow, unsigned short* __restrict__ MTb,
            float* __restrict__ W1) {
    __shared__ float tle[6][32][33];
    const int tid = threadIdx.x;
    const int k0 = blockIdx.y << 5, c0 = blockIdx.x << 5;
    const int ltx = tid & 31, lty = tid >> 5;  // load: c-lane, k-row group
#pragma unroll
    for (int m = 0; m < 6; ++m)
#pragma unroll
        for (int it = 0; it < 4; ++it) {
            int k = lty + (it << 3);
            tle[m][ltx][k] =
                Epow[(size_t)m * MATF + (size_t)(k0 + k) * DD + c0 + ltx];
        }
    __syncthreads();

    const int c = tid >> 3;          // 0..31
    const int kb = (tid & 7) << 2;   // 0,4,..28
    float em[6][4];
#pragma unroll
    for (int m = 0; m < 6; ++m)
#pragma unroll
        for (int u = 0; u < 4; ++u) em[m][u] = tle[m][c][kb + u];

    float w32[4];
    for (int j = 1; j <= 32; ++j) {
        float val[4];
#pragma unroll
        for (int u = 0; u < 4; ++u)
            val[u] = ((k0 + kb + u) == (c0 + c)) ? 1.f : 0.f;
        int coef = 1;
#pragma unroll
        for (int m = 1; m <= 6; ++m) {
            coef = coef * (j - m + 1) / m;  // exact binomial recurrence
            float cf = (float)(coef < 0 ? 0 : coef);
#pragma unroll
            for (int u = 0; u < 4; ++u) val[u] = fmaf(cf, em[m - 1][u], val[u]);
        }
        uint2 w;
        w.x = pack2bf(val[0], val[1]);
        w.y = pack2bf(val[2], val[3]);
        *(uint2*)(MTb + (size_t)(j - 1) * MATF + (size_t)(c0 + c) * DD + k0 + kb) = w;
        if (j == 32) {
            w32[0] = val[0]; w32[1] = val[1]; w32[2] = val[2]; w32[3] = val[3];
        }
    }
    // W1 = M_32 f32 in natural [k][c] layout, staged via LDS for coalescing
    __syncthreads();
    float* tw = &tle[0][0][0];
#pragma unroll
    for (int u = 0; u < 4; ++u) tw[(kb + u) * 33 + c] = w32[u];
    __syncthreads();
    const int wk = tid >> 3, wc = (tid & 7) << 2;
    float4 v = {tw[wk * 33 + wc], tw[wk * 33 + wc + 1], tw[wk * 33 + wc + 2],
                tw[wk * 33 + wc + 3]};
    *(float4*)(W1 + (size_t)(k0 + wk) * DD + c0 + wc) = v;
}

// Checkpoint scan level s (batched, proven r6): jobs mm < 2^s are Z-jobs
//   Z_{2^s+mm} = Z_mm @ W_{2^s} (Z_0 = z0) -> f32 out[:,32*dst-1,:] + bf16 Zb[dst]
// job mm == 2^s (s<3) squares W: Wtab[s] = W_{2^s} @ W_{2^s}. W_1 = comb's W1.
__global__ void __launch_bounds__(256)
scan_kernel(const float* __restrict__ z0, float* __restrict__ out,
            const float* __restrict__ W1, float* __restrict__ Wtab,
            unsigned short* __restrict__ Zb, int s) {
    const int nvec = 1 << s;
    const int mm = blockIdx.z;
    const float* W = (s == 0) ? W1 : Wtab + (size_t)(s - 1) * MATF;
    float acc[2][2];
    const int rowBase = blockIdx.y << 5, colBase = blockIdx.x << 5;
    const int r0 = rowBase + ((threadIdx.x >> 4) << 1);
    const int c0 = colBase + ((threadIdx.x & 15) << 1);
    if (mm < nvec) {
        const float* Asrc = mm ? out + (size_t)(32 * mm - 1) * DD : z0;
        int lda = mm ? (int)LDT : DD;
        g32_core(Asrc, lda, W, DD, rowBase, colBase, acc);
        const int dst = nvec + mm;  // 1..15
        float* Of = out + (size_t)(32 * dst - 1) * DD;
        unsigned short* Zo = Zb + (size_t)dst * MATF;
#pragma unroll
        for (int ii = 0; ii < 2; ++ii) {
            int r = r0 + ii;
            float2 v = {acc[ii][0], acc[ii][1]};
            *(float2*)(Of + (size_t)r * LDT + c0) = v;
            *(unsigned*)(Zo + (size_t)r * DD + c0) = pack2bf(v.x, v.y);
        }
    } else {
        g32_core(W, DD, W, DD, rowBase, colBase, acc);
        float* Cb = Wtab + (size_t)s * MATF;
#pragma unroll
        for (int ii = 0; ii < 2; ++ii) {
            int r = r0 + ii;
            *(float2*)(Cb + (size_t)r * DD + c0) = (float2){acc[ii][0], acc[ii][1]};
        }
    }
}

// Batched bf16 MFMA fill (proven r6/r8): 497 jobs; i = min(bz/31,15),
// j = bz - i*31 + 1. out[:, 32i+j-1, :] = Zb[i] @ M_j. 128x128 tile, 4 waves,
// single-buffered 32KB LDS, two-pass LDS-staged C write.
__global__ void __launch_bounds__(256)
fill_kernel(const unsigned short* __restrict__ Zb,
            const unsigned short* __restrict__ MTb,
            float* __restrict__ out) {
    __shared__ __align__(16) char pool[32768];
    const int bz = blockIdx.z;
    const int i = (bz >= 465) ? 15 : bz / 31;
    const int j = bz - i * 31 + 1;
    const int t = i * 32 + j - 1;
    const unsigned short* Zt = Zb + (size_t)i * MATF;
    const unsigned short* MT = MTb + (size_t)(j - 1) * MATF;

    const int tid = threadIdx.x;
    const int lane = tid & 63, wid = tid >> 6;
    const int rowBase = blockIdx.y * 128, colBase = blockIdx.x * 128;
    const int wr = (wid >> 1) * 64, wc = (wid & 1) * 64;

    int rowq[4], skq[4], ldsb[4];
#pragma unroll
    for (int q = 0; q < 4; ++q) {
        int c = q * 256 + wid * 64 + lane;
        int row = c >> 3;
        rowq[q] = row;
        skq[q] = ((c ^ (row & 7)) & 7) << 3;
        ldsb[q] = (q * 256 + wid * 64) << 4;
    }

    f32x4 acc[4][4];
#pragma unroll
    for (int a = 0; a < 4; ++a)
#pragma unroll
        for (int b = 0; b < 4; ++b) acc[a][b] = (f32x4){0.f, 0.f, 0.f, 0.f};

    auto stage = [&](int k0) {
#pragma unroll
        for (int q = 0; q < 4; ++q) {
            GLD16(Zt + (size_t)(rowBase + rowq[q]) * DD + k0 + skq[q], pool + ldsb[q]);
            GLD16(MT + (size_t)(colBase + rowq[q]) * DD + k0 + skq[q],
                  pool + 16384 + ldsb[q]);
        }
    };

    stage(0);
    for (int r = 0; r < 4; ++r) {
        __syncthreads();
        const char* asb = pool;
        const char* bsb = pool + 16384;
#pragma unroll
        for (int ks = 0; ks < 2; ++ks) {
            bf16x8 af[4], bg[4];
            const int kk = ks * 32 + (lane >> 4) * 8;
#pragma unroll
            for (int f = 0; f < 4; ++f) {
                int rr = wr + f * 16 + (lane & 15);
                af[f] = *(const bf16x8*)(asb + ((rr * 128 + kk * 2) ^ ((rr & 7) << 4)));
                int cc = wc + f * 16 + (lane & 15);
                bg[f] = *(const bf16x8*)(bsb + ((cc * 128 + kk * 2) ^ ((cc & 7) << 4)));
            }
#pragma unroll
            for (int fr = 0; fr < 4; ++fr)
#pragma unroll
                for (int fc = 0; fc < 4; ++fc)
                    acc[fr][fc] = __builtin_amdgcn_mfma_f32_16x16x32_bf16(
                        af[fr], bg[fc], acc[fr][fc], 0, 0, 0);
        }
        __syncthreads();
        if (r < 3) stage((r + 1) * 64);
    }

    float* Cs = (float*)pool;
    float* C = out + (size_t)t * DD;
#pragma unroll
    for (int hp = 0; hp < 2; ++hp) {
        __syncthreads();
        if (wr == hp * 64) {
#pragma unroll
            for (int fr = 0; fr < 4; ++fr) {
#pragma unroll
                for (int fc = 0; fc < 4; ++fc) {
                    int ccol = wc + fc * 16 + (lane & 15);
#pragma unroll
                    for (int ii = 0; ii < 4; ++ii) {
                        int lr = fr * 16 + ((lane >> 4) << 2) + ii;
                        int csw = ccol ^ (((lr >> 2) & 1) << 4);
                        Cs[lr * 128 + csw] = acc[fr][fc][ii];
                    }
                }
            }
        }
        __syncthreads();
#pragma unroll
        for (int it = 0; it < 8; ++it) {
            int chunk = it * 256 + tid;
            int row = chunk >> 5;
            int c4 = (chunk & 31) << 2;
            int csw = c4 ^ (((row >> 2) & 1) << 4);
            float4 v = *(const float4*)(Cs + row * 128 + csw);
            *(float4*)(C + (size_t)(rowBase + hp * 64 + row) * LDT + colBase + c4) = v;
        }
    }
}

// ---------------- fallback (tiny ws): proven g32 chain ----------------------
__global__ void prep_kernel(const float* __restrict__ K,
                            const float* __restrict__ log_dt,
                            float* __restrict__ A) {
    int idx = blockIdx.x * blockDim.x + threadIdx.x;
    A[idx] = 0.5f * expf(log_dt[0]) * K[idx];
}

template <int EPI>
__global__ void __launch_bounds__(256)
g32_kernel(const float* A, const float* B, float* C, const float* E, float* C2,
           int lda, int ldb, int ldc, long long sA, long long sB, long long sC) {
    float acc[2][2];
    const int rowBase = blockIdx.y << 5, colBase = blockIdx.x << 5;
    g32_core(A + blockIdx.z * sA, lda, B + blockIdx.z * sB, ldb, rowBase, colBase, acc);
    float* Cb = C + blockIdx.z * sC;
    const int r0 = rowBase + ((threadIdx.x >> 4) << 1);
    const int c0 = colBase + ((threadIdx.x & 15) << 1);
#pragma unroll
    for (int i = 0; i < 2; ++i) {
        int r = r0 + i;
        float2 v;
        if (EPI == 2) {
            float e0 = E[(size_t)r * DD + c0], e1 = E[(size_t)r * DD + c0 + 1];
            v.x = acc[i][0] + 2.f * e0 + (r == c0 ? 1.f : 0.f);
            v.y = acc[i][1] + 2.f * e1 + (r == c0 + 1 ? 1.f : 0.f);
        } else {
            v.x = acc[i][0];
            v.y = acc[i][1];
        }
        *(float2*)(Cb + (size_t)r * ldc + c0) = v;
        if (EPI == 1) {
            float e0 = E[(size_t)r * DD + c0], e1 = E[(size_t)r * DD + c0 + 1];
            float2 w;
            w.x = 2.f * acc[i][0] + 2.f * e0 + (r == c0 ? 2.f : 0.f);
            w.y = 2.f * acc[i][1] + 2.f * e1 + (r == c0 + 1 ? 2.f : 0.f);
            *(float2*)(C2 + (size_t)r * DD + c0) = w;
        }
    }
}

// ---------------- launch ----------------------------------------------------
extern "C" void kernel_launch(void* const* d_in, const int* in_sizes, int n_in,
                              void* d_out, int out_size, void* d_ws, size_t ws_size,
                              hipStream_t stream) {
    const float* z0 = (const float*)d_in[0];
    const float* Kmat = (const float*)d_in[1];
    const float* log_dt = (const float*)d_in[2];
    float* out = (float*)d_out;

    dim3 blk(256);

    // ws: A2 | Bop | Epow[6] (E,E2..E6) | W1 | Wtab[3] f32 | MTb[32] | Zb[16] bf16
    float* A2 = (float*)d_ws;
    float* Bop = A2 + MATF;
    float* Epow = Bop + MATF;
    float* W1 = Epow + (size_t)6 * MATF;
    float* Wtab = W1 + MATF;
    unsigned short* MTb = (unsigned short*)(Wtab + (size_t)3 * MATF);
    unsigned short* Zb = MTb + (size_t)32 * MATF;
    const size_t need = (size_t)12 * MATF * 4 + (size_t)48 * MATF * 2;

    if (ws_size >= need) {
        dim3 g(8, 8, 1);
        // Neumann order-4 -> E = Kd - I (2 launches)
        n1_kernel<<<g, blk, 0, stream>>>(Kmat, log_dt, z0, A2, Bop, Zb);
        n2_kernel<<<g, blk, 0, stream>>>(A2, Bop, Kmat, log_dt, Epow);

        // E-powers: E2 ; {E3=E@E2, E4=E2@E2} ; {E5=E2@E3, E6=E3@E3}
        gpow_kernel<<<g, blk, 0, stream>>>(Epow, Epow, Epow + MATF, 0, 0, 0);
        gpow_kernel<<<dim3(8, 8, 2), blk, 0, stream>>>(
            Epow, Epow + MATF, Epow + 2 * (size_t)MATF, MATF, 0, MATF);
        gpow_kernel<<<dim3(8, 8, 2), blk, 0, stream>>>(
            Epow + MATF, Epow + 2 * (size_t)MATF, Epow + 4 * (size_t)MATF,
            MATF, 0, MATF);

        // All 32 M-tables (bf16 transposed) + W1 = M_32 f32, one launch
        comb_kernel<<<g, blk, 0, stream>>>(Epow, MTb, W1);

        // checkpoint scan: 4 batched levels (Z-jobs + W-squaring per level)
        const int njobs[4] = {2, 3, 5, 8};
        for (int s = 0; s < 4; ++s)
            scan_kernel<<<dim3(8, 8, njobs[s]), blk, 0, stream>>>(
                z0, out, W1, Wtab, Zb, s);

        // All 497 remaining timesteps in one batched MFMA launch
        fill_kernel<<<dim3(2, 2, 497), blk, 0, stream>>>(Zb, MTb, out);
        return;
    }

    // Minimal fallback (tiny ws): Kd then 512 chained GEMMs (f32, proven core).
    float* A = (float*)d_ws;
    float* A2f = A + MATF;
    float* Bopf = A2f + MATF;
    float* Kd = Bopf + MATF;
    prep_kernel<<<MATF / 256, blk, 0, stream>>>(Kmat, log_dt, A);
    dim3 g(8, 8, 1);
    g32_kernel<1><<<g, blk, 0, stream>>>(A, A, A2f, A, Bopf, DD, DD, DD, 0, 0, 0);
    g32_kernel<2><<<g, blk, 0, stream>>>(A2f, Bopf, Kd, A, (float*)0, DD, DD, DD, 0, 0, 0);
    for (int t = 0; t < TT; ++t) {
        const float* Ain = (t == 0) ? z0 : out + (size_t)(t - 1) * DD;
        int lda = (t == 0) ? DD : (int)LDT;
        g32_kernel<0><<<g, blk, 0, stream>>>(Ain, Kd, out + (size_t)t * DD,
                                             (const float*)0, (float*)0,
                                             lda, DD, (int)LDT, 0, 0, 0);
    }
}

// Round 10
// 120.034 us; speedup vs baseline: 2.6953x; 1.0036x over previous
//
#include <hip/hip_runtime.h>

// Koopman bilinear rollout: preds[b,t,d] = (z0 @ Kd^{t+1})[b,d], D=B=256, T=512.
// Kd = (I-A)^-1(I+A), A=0.5*dt*K -> order-4 Neumann (2 launches, proven r2-r9).
// r10: E-powers E^2..E^8 in 3 GEMM stages (3rd = batch 4); comb writes all 32
// bf16-T M-tables (m<=8) AND W1=(I+E)^32, W2=(I+E)^64, W3=(I+E)^96 in f32;
// checkpoint scan collapses to 3 batched levels (L0: Z1..Z3 + W4,W6;
// L1: Z4..Z9 + W12; L2: Z10..Z15). One batched bf16-MFMA fill (proven r6/r8)
// covers the remaining 497 timesteps. 10 launches total.
// DEAD ENDS (do not retry): persistent kernel + grid barrier -- r5 acquire-poll
// 392us, r7 relaxed-poll+fence 289us; cache-maintenance storm either way.

#define DD 256
#define TT 512
#define MATF (DD * DD)
#define LDT ((size_t)TT * (size_t)DD)

typedef __attribute__((ext_vector_type(8))) short bf16x8;
typedef __attribute__((ext_vector_type(4))) float f32x4;

#define GLD16(g, l)                                                  \
    __builtin_amdgcn_global_load_lds(                                \
        (const __attribute__((address_space(1))) void*)(g),          \
        (__attribute__((address_space(3))) void*)(l), 16, 0, 0)

static __device__ __forceinline__ unsigned short f2bf(float f) {
    unsigned int u = __float_as_uint(f);
    u += 0x7fffu + ((u >> 16) & 1u);
    return (unsigned short)(u >> 16);
}
static __device__ __forceinline__ unsigned pack2bf(float a, float b) {
    return (unsigned)f2bf(a) | ((unsigned)f2bf(b) << 16);
}

// ---- 32x32-tile f32 GEMM core: 256 threads, K=256, K_BLK=64, reg prefetch ----
// (byte-identical to the proven r3-r9 core)
__device__ __forceinline__ void g32_core(const float* __restrict__ Ab, int lda,
                                         const float* __restrict__ Bb, int ldb,
                                         int rowBase, int colBase, float acc[2][2]) {
    __shared__ __align__(16) float As[64 * 38];
    __shared__ __align__(16) float Bs[64 * 40];
    const int tid = threadIdx.x;
    const int tx = tid & 15, ty = tid >> 4;
    const int am = tid >> 4;
    const int ak = (tid & 15) << 2;
    const int bk = tid >> 3;
    const int bn = (tid & 7) << 2;

    acc[0][0] = acc[0][1] = acc[1][0] = acc[1][1] = 0.f;

    float4 pa0 = *(const float4*)(Ab + (size_t)(rowBase + am) * lda + ak);
    float4 pa1 = *(const float4*)(Ab + (size_t)(rowBase + am + 16) * lda + ak);
    float4 pb0 = *(const float4*)(Bb + (size_t)bk * ldb + colBase + bn);
    float4 pb1 = *(const float4*)(Bb + (size_t)(bk + 32) * ldb + colBase + bn);

    for (int k0 = 0; k0 < DD; k0 += 64) {
        As[(ak + 0) * 38 + am] = pa0.x;
        As[(ak + 1) * 38 + am] = pa0.y;
        As[(ak + 2) * 38 + am] = pa0.z;
        As[(ak + 3) * 38 + am] = pa0.w;
        As[(ak + 0) * 38 + am + 16] = pa1.x;
        As[(ak + 1) * 38 + am + 16] = pa1.y;
        As[(ak + 2) * 38 + am + 16] = pa1.z;
        As[(ak + 3) * 38 + am + 16] = pa1.w;
        *(float4*)(&Bs[bk * 40 + bn]) = pb0;
        *(float4*)(&Bs[(bk + 32) * 40 + bn]) = pb1;
        __syncthreads();
        if (k0 + 64 < DD) {
            pa0 = *(const float4*)(Ab + (size_t)(rowBase + am) * lda + k0 + 64 + ak);
            pa1 = *(const float4*)(Ab + (size_t)(rowBase + am + 16) * lda + k0 + 64 + ak);
            pb0 = *(const float4*)(Bb + (size_t)(bk + k0 + 64) * ldb + colBase + bn);
            pb1 = *(const float4*)(Bb + (size_t)(bk + 32 + k0 + 64) * ldb + colBase + bn);
        }
#pragma unroll
        for (int kk = 0; kk < 64; ++kk) {
            float2 a2 = *(const float2*)(&As[kk * 38 + (ty << 1)]);
            float2 b2 = *(const float2*)(&Bs[kk * 40 + (tx << 1)]);
            acc[0][0] = fmaf(a2.x, b2.x, acc[0][0]);
            acc[0][1] = fmaf(a2.x, b2.y, acc[0][1]);
            acc[1][0] = fmaf(a2.y, b2.x, acc[1][0]);
            acc[1][1] = fmaf(a2.y, b2.y, acc[1][1]);
        }
        __syncthreads();
    }
}

// N1: acc = K@K. A2 = cs^2*acc ; Bop = 2I + 2cs*K + 2cs^2*acc ; Zb0 = bf16(z0)
__global__ void __launch_bounds__(256)
n1_kernel(const float* __restrict__ K, const float* __restrict__ log_dt,
          const float* __restrict__ z0, float* __restrict__ A2,
          float* __restrict__ Bop, unsigned short* __restrict__ Zb0) {
    const float cs = 0.5f * expf(log_dt[0]);
    {
        int b = ((blockIdx.y * 8 + blockIdx.x) * 256 + threadIdx.x) * 4;
        uint2 w;
        w.x = pack2bf(z0[b], z0[b + 1]);
        w.y = pack2bf(z0[b + 2], z0[b + 3]);
        *(uint2*)(Zb0 + b) = w;
    }
    float acc[2][2];
    const int rowBase = blockIdx.y << 5, colBase = blockIdx.x << 5;
    g32_core(K, DD, K, DD, rowBase, colBase, acc);
    const float cs2 = cs * cs;
    const int r0 = rowBase + ((threadIdx.x >> 4) << 1);
    const int c0 = colBase + ((threadIdx.x & 15) << 1);
#pragma unroll
    for (int i = 0; i < 2; ++i) {
        int r = r0 + i;
        float e0 = K[(size_t)r * DD + c0], e1 = K[(size_t)r * DD + c0 + 1];
        float p0 = cs2 * acc[i][0], p1 = cs2 * acc[i][1];
        *(float2*)(A2 + (size_t)r * DD + c0) = (float2){p0, p1};
        float2 w;
        w.x = 2.f * p0 + 2.f * cs * e0 + (r == c0 ? 2.f : 0.f);
        w.y = 2.f * p1 + 2.f * cs * e1 + (r == c0 + 1 ? 2.f : 0.f);
        *(float2*)(Bop + (size_t)r * DD + c0) = w;
    }
}

// N2: E = Kd - I = A2@Bop + 2cs*K   (f32, natural layout)
__global__ void __launch_bounds__(256)
n2_kernel(const float* __restrict__ A2, const float* __restrict__ Bop,
          const float* __restrict__ K, const float* __restrict__ log_dt,
          float* __restrict__ E) {
    const float cs = 0.5f * expf(log_dt[0]);
    float acc[2][2];
    const int rowBase = blockIdx.y << 5, colBase = blockIdx.x << 5;
    g32_core(A2, DD, Bop, DD, rowBase, colBase, acc);
    const int r0 = rowBase + ((threadIdx.x >> 4) << 1);
    const int c0 = colBase + ((threadIdx.x & 15) << 1);
#pragma unroll
    for (int i = 0; i < 2; ++i) {
        int r = r0 + i;
        float e0 = K[(size_t)r * DD + c0], e1 = K[(size_t)r * DD + c0 + 1];
        float2 v;
        v.x = acc[i][0] + 2.f * cs * e0;
        v.y = acc[i][1] + 2.f * cs * e1;
        *(float2*)(E + (size_t)r * DD + c0) = v;
    }
}

// Generic batched 256^3 f32 GEMM (plain epilogue) for E-power stages 1-2.
__global__ void __launch_bounds__(256)
gpow_kernel(const float* __restrict__ A, const float* __restrict__ B,
            float* __restrict__ C, long long sA, long long sB, long long sC) {
    float acc[2][2];
    const int rowBase = blockIdx.y << 5, colBase = blockIdx.x << 5;
    g32_core(A + blockIdx.z * sA, DD, B + blockIdx.z * sB, DD, rowBase, colBase, acc);
    float* Cb = C + blockIdx.z * sC;
    const int r0 = rowBase + ((threadIdx.x >> 4) << 1);
    const int c0 = colBase + ((threadIdx.x & 15) << 1);
#pragma unroll
    for (int i = 0; i < 2; ++i) {
        int r = r0 + i;
        *(float2*)(Cb + (size_t)r * DD + c0) = (float2){acc[i][0], acc[i][1]};
    }
}

// E-power stage 3 (batch 4): E5=E2@E3, E6=E3@E3, E7=E3@E4, E8=E4@E4
__global__ void __launch_bounds__(256)
gpow4_kernel(float* __restrict__ Epow) {
    static const int sa[4] = {1, 2, 2, 3};
    static const int sb[4] = {2, 2, 3, 3};
    static const int sc[4] = {4, 5, 6, 7};
    const int z = blockIdx.z;
    float acc[2][2];
    const int rowBase = blockIdx.y << 5, colBase = blockIdx.x << 5;
    g32_core(Epow + (size_t)sa[z] * MATF, DD, Epow + (size_t)sb[z] * MATF, DD,
             rowBase, colBase, acc);
    float* Cb = Epow + (size_t)sc[z] * MATF;
    const int r0 = rowBase + ((threadIdx.x >> 4) << 1);
    const int c0 = colBase + ((threadIdx.x & 15) << 1);
#pragma unroll
    for (int i = 0; i < 2; ++i) {
        int r = r0 + i;
        *(float2*)(Cb + (size_t)r * DD + c0) = (float2){acc[i][0], acc[i][1]};
    }
}

// comb: M_j = (I+E)^j = I + sum_{m=1}^{8} C(j,m) E^m, j=1..32 -> bf16 MTb[j][c][k]
// plus f32 W1=(I+E)^32, W2=(I+E)^64, W3=(I+E)^96 (natural [k][c] layout).
// Truncation (entry scale): W1 ~1e-9, W2 ~9e-7, W3 ~4e-5 -- all << bf16 noise.
__global__ void __launch_bounds__(256)
comb_kernel(const float* __restrict__ Epow, unsigned short* __restrict__ MTb,
            float* __restrict__ W1, float* __restrict__ W2,
            float* __restrict__ W3) {
    __shared__ float tle[8][32][33];
    const int tid = threadIdx.x;
    const int k0 = blockIdx.y << 5, c0 = blockIdx.x << 5;
    const int ltx = tid & 31, lty = tid >> 5;
#pragma unroll
    for (int m = 0; m < 8; ++m)
#pragma unroll
        for (int it = 0; it < 4; ++it) {
            int k = lty + (it << 3);
            tle[m][ltx][k] =
                Epow[(size_t)m * MATF + (size_t)(k0 + k) * DD + c0 + ltx];
        }
    __syncthreads();

    const int c = tid >> 3;          // 0..31
    const int kb = (tid & 7) << 2;   // 0,4,..28
    float em[8][4];
#pragma unroll
    for (int m = 0; m < 8; ++m)
#pragma unroll
        for (int u = 0; u < 4; ++u) em[m][u] = tle[m][c][kb + u];

    float diag[4];
#pragma unroll
    for (int u = 0; u < 4; ++u)
        diag[u] = ((k0 + kb + u) == (c0 + c)) ? 1.f : 0.f;

    float w32[4];
    for (int j = 1; j <= 32; ++j) {
        float val[4] = {diag[0], diag[1], diag[2], diag[3]};
        long long coef = 1;
#pragma unroll
        for (int m = 1; m <= 8; ++m) {
            coef = coef * (j - m + 1) / m;  // exact binomial recurrence
            float cf = (float)(coef < 0 ? 0 : coef);
#pragma unroll
            for (int u = 0; u < 4; ++u) val[u] = fmaf(cf, em[m - 1][u], val[u]);
        }
        uint2 w;
        w.x = pack2bf(val[0], val[1]);
        w.y = pack2bf(val[2], val[3]);
        *(uint2*)(MTb + (size_t)(j - 1) * MATF + (size_t)(c0 + c) * DD + k0 + kb) = w;
        if (j == 32) {
            w32[0] = val[0]; w32[1] = val[1]; w32[2] = val[2]; w32[3] = val[3];
        }
    }
    // W2 (n=64), W3 (n=96): same series, double coefficient recurrence
    float w64[4] = {diag[0], diag[1], diag[2], diag[3]};
    float w96[4] = {diag[0], diag[1], diag[2], diag[3]};
    {
        double c64 = 1.0, c96 = 1.0;
#pragma unroll
        for (int m = 1; m <= 8; ++m) {
            c64 = c64 * (double)(64 - m + 1) / (double)m;
            c96 = c96 * (double)(96 - m + 1) / (double)m;
            float f64 = (float)c64, f96 = (float)c96;
#pragma unroll
            for (int u = 0; u < 4; ++u) {
                w64[u] = fmaf(f64, em[m - 1][u], w64[u]);
                w96[u] = fmaf(f96, em[m - 1][u], w96[u]);
            }
        }
    }
    // three LDS-transpose passes -> coalesced f32 stores in [k][c] layout
    float* tw = &tle[0][0][0];
    const int wk = tid >> 3, wc = (tid & 7) << 2;
    float* Wd[3] = {W1, W2, W3};
    float* Ws[3] = {w32, w64, w96};
#pragma unroll
    for (int p = 0; p < 3; ++p) {
        __syncthreads();
#pragma unroll
        for (int u = 0; u < 4; ++u) tw[(kb + u) * 33 + c] = Ws[p][u];
        __syncthreads();
        float4 v = {tw[wk * 33 + wc], tw[wk * 33 + wc + 1],
                    tw[wk * 33 + wc + 2], tw[wk * 33 + wc + 3]};
        *(float4*)(Wd[p] + (size_t)(k0 + wk) * DD + c0 + wc) = v;
    }
}

// 3-level checkpoint scan. Job tables (a: 0=z0, 1..15=Z_mm from out,
// 16+k=Wp[k]; b: index into Wp; d: 1..15=Z_dst, 19/20/21=Wtab slot 0/1/2).
// Wp = {W1, W2, W3, Wtab+0 (W4), Wtab+1 (W6), Wtab+2 (W12)}.
// L0: Z1..Z3, W4=W2^2, W6=W3^2 ; L1: Z4..Z9, W12=W6^2 ; L2: Z10..Z15.
__global__ void __launch_bounds__(256)
scan3_kernel(const float* __restrict__ z0, float* __restrict__ out,
             const float* __restrict__ W1, const float* __restrict__ W2,
             const float* __restrict__ W3, float* __restrict__ Wtab,
             unsigned short* __restrict__ Zb, int level) {
    static const signed char JA[3][7] = {{0, 0, 0, 17, 18, 0, 0},
                                         {0, 1, 2, 3, 2, 3, 20},
                                         {4, 5, 0, 1, 2, 3, 0}};
    static const signed char JB[3][7] = {{0, 1, 2, 1, 2, 0, 0},
                                         {3, 3, 3, 3, 4, 4, 4},
                                         {4, 4, 5, 5, 5, 5, 0}};
    static const signed char JD[3][7] = {{1, 2, 3, 19, 20, 0, 0},
                                         {4, 5, 6, 7, 8, 9, 21},
                                         {10, 11, 12, 13, 14, 15, 0}};
    const float* Wp[6] = {W1, W2, W3, Wtab, Wtab + MATF, Wtab + 2 * (size_t)MATF};
    const int jz = blockIdx.z;
    const int a = JA[level][jz], b = JB[level][jz], d = JD[level][jz];

    const float* Asrc;
    int lda;
    if (a == 0) { Asrc = z0; lda = DD; }
    else if (a < 16) { Asrc = out + (size_t)(32 * a - 1) * DD; lda = (int)LDT; }
    else { Asrc = Wp[a - 16]; lda = DD; }

    float acc[2][2];
    const int rowBase = blockIdx.y << 5, colBase = blockIdx.x << 5;
    g32_core(Asrc, lda, Wp[b], DD, rowBase, colBase, acc);

    const int r0 = rowBase + ((threadIdx.x >> 4) << 1);
    const int c0 = colBase + ((threadIdx.x & 15) << 1);
    if (d < 16) {
        float* Of = out + (size_t)(32 * d - 1) * DD;
        unsigned short* Zo = Zb + (size_t)d * MATF;
#pragma unroll
        for (int ii = 0; ii < 2; ++ii) {
            int r = r0 + ii;
            float2 v = {acc[ii][0], acc[ii][1]};
            *(float2*)(Of + (size_t)r * LDT + c0) = v;
            *(unsigned*)(Zo + (size_t)r * DD + c0) = pack2bf(v.x, v.y);
        }
    } else {
        float* Cb = Wtab + (size_t)(d - 19) * MATF;
#pragma unroll
        for (int ii = 0; ii < 2; ++ii) {
            int r = r0 + ii;
            *(float2*)(Cb + (size_t)r * DD + c0) = (float2){acc[ii][0], acc[ii][1]};
        }
    }
}

// Batched bf16 MFMA fill (proven r6/r8): 497 jobs; i = min(bz/31,15),
// j = bz - i*31 + 1. out[:, 32i+j-1, :] = Zb[i] @ M_j. 128x128 tile, 4 waves,
// single-buffered 32KB LDS, two-pass LDS-staged C write.
__global__ void __launch_bounds__(256)
fill_kernel(const unsigned short* __restrict__ Zb,
            const unsigned short* __restrict__ MTb,
            float* __restrict__ out) {
    __shared__ __align__(16) char pool[32768];
    const int bz = blockIdx.z;
    const int i = (bz >= 465) ? 15 : bz / 31;
    const int j = bz - i * 31 + 1;
    const int t = i * 32 + j - 1;
    const unsigned short* Zt = Zb + (size_t)i * MATF;
    const unsigned short* MT = MTb + (size_t)(j - 1) * MATF;

    const int tid = threadIdx.x;
    const int lane = tid & 63, wid = tid >> 6;
    const int rowBase = blockIdx.y * 128, colBase = blockIdx.x * 128;
    const int wr = (wid >> 1) * 64, wc = (wid & 1) * 64;

    int rowq[4], skq[4], ldsb[4];
#pragma unroll
    for (int q = 0; q < 4; ++q) {
        int c = q * 256 + wid * 64 + lane;
        int row = c >> 3;
        rowq[q] = row;
        skq[q] = ((c ^ (row & 7)) & 7) << 3;
        ldsb[q] = (q * 256 + wid * 64) << 4;
    }

    f32x4 acc[4][4];
#pragma unroll
    for (int a = 0; a < 4; ++a)
#pragma unroll
        for (int b = 0; b < 4; ++b) acc[a][b] = (f32x4){0.f, 0.f, 0.f, 0.f};

    auto stage = [&](int k0) {
#pragma unroll
        for (int q = 0; q < 4; ++q) {
            GLD16(Zt + (size_t)(rowBase + rowq[q]) * DD + k0 + skq[q], pool + ldsb[q]);
            GLD16(MT + (size_t)(colBase + rowq[q]) * DD + k0 + skq[q],
                  pool + 16384 + ldsb[q]);
        }
    };

    stage(0);
    for (int r = 0; r < 4; ++r) {
        __syncthreads();
        const char* asb = pool;
        const char* bsb = pool + 16384;
#pragma unroll
        for (int ks = 0; ks < 2; ++ks) {
            bf16x8 af[4], bg[4];
            const int kk = ks * 32 + (lane >> 4) * 8;
#pragma unroll
            for (int f = 0; f < 4; ++f) {
                int rr = wr + f * 16 + (lane & 15);
                af[f] = *(const bf16x8*)(asb + ((rr * 128 + kk * 2) ^ ((rr & 7) << 4)));
                int cc = wc + f * 16 + (lane & 15);
                bg[f] = *(const bf16x8*)(bsb + ((cc * 128 + kk * 2) ^ ((cc & 7) << 4)));
            }
#pragma unroll
            for (int fr = 0; fr < 4; ++fr)
#pragma unroll
                for (int fc = 0; fc < 4; ++fc)
                    acc[fr][fc] = __builtin_amdgcn_mfma_f32_16x16x32_bf16(
                        af[fr], bg[fc], acc[fr][fc], 0, 0, 0);
        }
        __syncthreads();
        if (r < 3) stage((r + 1) * 64);
    }

    float* Cs = (float*)pool;
    float* C = out + (size_t)t * DD;
#pragma unroll
    for (int hp = 0; hp < 2; ++hp) {
        __syncthreads();
        if (wr == hp * 64) {
#pragma unroll
            for (int fr = 0; fr < 4; ++fr) {
#pragma unroll
                for (int fc = 0; fc < 4; ++fc) {
                    int ccol = wc + fc * 16 + (lane & 15);
#pragma unroll
                    for (int ii = 0; ii < 4; ++ii) {
                        int lr = fr * 16 + ((lane >> 4) << 2) + ii;
                        int csw = ccol ^ (((lr >> 2) & 1) << 4);
                        Cs[lr * 128 + csw] = acc[fr][fc][ii];
                    }
                }
            }
        }
        __syncthreads();
#pragma unroll
        for (int it = 0; it < 8; ++it) {
            int chunk = it * 256 + tid;
            int row = chunk >> 5;
            int c4 = (chunk & 31) << 2;
            int csw = c4 ^ (((row >> 2) & 1) << 4);
            float4 v = *(const float4*)(Cs + row * 128 + csw);
            *(float4*)(C + (size_t)(rowBase + hp * 64 + row) * LDT + colBase + c4) = v;
        }
    }
}

// ---------------- fallback (tiny ws): proven g32 chain ----------------------
__global__ void prep_kernel(const float* __restrict__ K,
                            const float* __restrict__ log_dt,
                            float* __restrict__ A) {
    int idx = blockIdx.x * blockDim.x + threadIdx.x;
    A[idx] = 0.5f * expf(log_dt[0]) * K[idx];
}

template <int EPI>
__global__ void __launch_bounds__(256)
g32_kernel(const float* A, const float* B, float* C, const float* E, float* C2,
           int lda, int ldb, int ldc, long long sA, long long sB, long long sC) {
    float acc[2][2];
    const int rowBase = blockIdx.y << 5, colBase = blockIdx.x << 5;
    g32_core(A + blockIdx.z * sA, lda, B + blockIdx.z * sB, ldb, rowBase, colBase, acc);
    float* Cb = C + blockIdx.z * sC;
    const int r0 = rowBase + ((threadIdx.x >> 4) << 1);
    const int c0 = colBase + ((threadIdx.x & 15) << 1);
#pragma unroll
    for (int i = 0; i < 2; ++i) {
        int r = r0 + i;
        float2 v;
        if (EPI == 2) {
            float e0 = E[(size_t)r * DD + c0], e1 = E[(size_t)r * DD + c0 + 1];
            v.x = acc[i][0] + 2.f * e0 + (r == c0 ? 1.f : 0.f);
            v.y = acc[i][1] + 2.f * e1 + (r == c0 + 1 ? 1.f : 0.f);
        } else {
            v.x = acc[i][0];
            v.y = acc[i][1];
        }
        *(float2*)(Cb + (size_t)r * ldc + c0) = v;
        if (EPI == 1) {
            float e0 = E[(size_t)r * DD + c0], e1 = E[(size_t)r * DD + c0 + 1];
            float2 w;
            w.x = 2.f * acc[i][0] + 2.f * e0 + (r == c0 ? 2.f : 0.f);
            w.y = 2.f * acc[i][1] + 2.f * e1 + (r == c0 + 1 ? 2.f : 0.f);
            *(float2*)(C2 + (size_t)r * DD + c0) = w;
        }
    }
}

// ---------------- launch ----------------------------------------------------
extern "C" void kernel_launch(void* const* d_in, const int* in_sizes, int n_in,
                              void* d_out, int out_size, void* d_ws, size_t ws_size,
                              hipStream_t stream) {
    const float* z0 = (const float*)d_in[0];
    const float* Kmat = (const float*)d_in[1];
    const float* log_dt = (const float*)d_in[2];
    float* out = (float*)d_out;

    dim3 blk(256);

    // ws: A2 | Bop | Epow[8] (E..E8) | W1 | W2 | W3 | Wtab[3] f32
    //     | MTb[32] | Zb[16] bf16
    float* A2 = (float*)d_ws;
    float* Bop = A2 + MATF;
    float* Epow = Bop + MATF;
    float* W1 = Epow + (size_t)8 * MATF;
    float* W2 = W1 + MATF;
    float* W3 = W2 + MATF;
    float* Wtab = W3 + MATF;
    unsigned short* MTb = (unsigned short*)(Wtab + (size_t)3 * MATF);
    unsigned short* Zb = MTb + (size_t)32 * MATF;
    const size_t need = (size_t)16 * MATF * 4 + (size_t)48 * MATF * 2;

    if (ws_size >= need) {
        dim3 g(8, 8, 1);
        // Neumann order-4 -> E = Kd - I (2 launches)
        n1_kernel<<<g, blk, 0, stream>>>(Kmat, log_dt, z0, A2, Bop, Zb);
        n2_kernel<<<g, blk, 0, stream>>>(A2, Bop, Kmat, log_dt, Epow);

        // E-powers: E2 ; {E3,E4} ; {E5,E6,E7,E8}
        gpow_kernel<<<g, blk, 0, stream>>>(Epow, Epow, Epow + MATF, 0, 0, 0);
        gpow_kernel<<<dim3(8, 8, 2), blk, 0, stream>>>(
            Epow, Epow + MATF, Epow + 2 * (size_t)MATF, MATF, 0, MATF);
        gpow4_kernel<<<dim3(8, 8, 4), blk, 0, stream>>>(Epow);

        // All 32 M-tables (bf16-T) + W1/W2/W3 f32, one launch
        comb_kernel<<<g, blk, 0, stream>>>(Epow, MTb, W1, W2, W3);

        // checkpoint scan: 3 batched levels
        const int njobs[3] = {5, 7, 6};
        for (int s = 0; s < 3; ++s)
            scan3_kernel<<<dim3(8, 8, njobs[s]), blk, 0, stream>>>(
                z0, out, W1, W2, W3, Wtab, Zb, s);

        // All 497 remaining timesteps in one batched MFMA launch
        fill_kernel<<<dim3(2, 2, 497), blk, 0, stream>>>(Zb, MTb, out);
        return;
    }

    // Minimal fallback (tiny ws): Kd then 512 chained GEMMs (f32, proven core).
    float* A = (float*)d_ws;
    float* A2f = A + MATF;
    float* Bopf = A2f + MATF;
    float* Kd = Bopf + MATF;
    prep_kernel<<<MATF / 256, blk, 0, stream>>>(Kmat, log_dt, A);
    dim3 g(8, 8, 1);
    g32_kernel<1><<<g, blk, 0, stream>>>(A, A, A2f, A, Bopf, DD, DD, DD, 0, 0, 0);
    g32_kernel<2><<<g, blk, 0, stream>>>(A2f, Bopf, Kd, A, (float*)0, DD, DD, DD, 0, 0, 0);
    for (int t = 0; t < TT; ++t) {
        const float* Ain = (t == 0) ? z0 : out + (size_t)(t - 1) * DD;
        int lda = (t == 0) ? DD : (int)LDT;
        g32_kernel<0><<<g, blk, 0, stream>>>(Ain, Kd, out + (size_t)t * DD,
                                             (const float*)0, (float*)0,
                                             lda, DD, (int)LDT, 0, 0, 0);
    }
}